// Round 4
// baseline (595.769 us; speedup 1.0000x reference)
//
#include <hip/hip_runtime.h>

typedef unsigned short u16;
typedef unsigned int u32;
typedef __bf16 bf16x8 __attribute__((ext_vector_type(8)));
typedef float f32x4 __attribute__((ext_vector_type(4)));

#define MFMA16 __builtin_amdgcn_mfma_f32_16x16x32_bf16

// B=4, N=1024, M=1024, D=1024, KV=1024, H=16, HD=64
// Interface dtypes per harness contract: inputs fp32 (detector hedges bf16),
// mask int32 (detector hedges u8/bf16/fp32), outputs fp32.

__device__ __forceinline__ float b2f(u16 u){ u32 x = ((u32)u)<<16; float f; __builtin_memcpy(&f,&x,4); return f; }
__device__ __forceinline__ u16 f2b(float f){ u32 x; __builtin_memcpy(&x,&f,4); return (u16)((x + 0x7fffu + ((x>>16)&1u)) >> 16); }
__device__ __forceinline__ bf16x8 ldf(const u16* p){ uint4 v = *(const uint4*)p; return __builtin_bit_cast(bf16x8, v); }
__device__ __forceinline__ u32 pk(u16 a, u16 b){ return (u32)a | ((u32)b<<16); }

// Async global->LDS: 16B per lane, dest = wave-uniform base + lane*16 (m97 pattern).
__device__ __forceinline__ void stage16(const u16* g, u16* l) {
  __builtin_amdgcn_global_load_lds(
      (const __attribute__((address_space(1))) void*)g,
      (__attribute__((address_space(3))) void*)l, 16, 0, 0);
}

// Load 8 consecutive logical elements of a float input as packed bf16 (uint4).
__device__ __forceinline__ uint4 ld8(const void* base, size_t off, int f32) {
  if (f32) {
    const float* p = (const float*)base + off;
    f32x4 a = *(const f32x4*)p;
    f32x4 b = *(const f32x4*)(p + 4);
    uint4 r;
    r.x = pk(f2b(a[0]), f2b(a[1]));
    r.y = pk(f2b(a[2]), f2b(a[3]));
    r.z = pk(f2b(b[0]), f2b(b[1]));
    r.w = pk(f2b(b[2]), f2b(b[3]));
    return r;
  }
  return *(const uint4*)((const u16*)base + off);
}
__device__ __forceinline__ float lds1(const void* base, size_t off, int f32) {
  return f32 ? ((const float*)base)[off] : b2f(((const u16*)base)[off]);
}

// ---------------------------------------------------------------------------
// Input dtype detection (majority vote over 1024 words). flag: 1=fp32, 0=bf16.
// ---------------------------------------------------------------------------
__global__ __launch_bounds__(256) void detect_dtype(const u32* __restrict__ q, int* __restrict__ flag) {
  __shared__ int cnt;
  if (threadIdx.x == 0) cnt = 0;
  __syncthreads();
  int c = 0;
#pragma unroll
  for (int i = 0; i < 4; i++) {
    u32 w = q[threadIdx.x + i*256];
    u32 e = (w >> 7) & 0xFFu;
    c += (e >= 100u && e <= 140u) ? 1 : 0;
  }
#pragma unroll
  for (int m = 1; m <= 32; m <<= 1) c += __shfl_xor(c, m);
  if ((threadIdx.x & 63) == 0) atomicAdd(&cnt, c);
  __syncthreads();
  if (threadIdx.x == 0) flag[0] = (cnt < 512) ? 1 : 0;
}

// ---------------------------------------------------------------------------
// Mask dtype auto-detection + conversion to float {0, -inf}.
// ---------------------------------------------------------------------------
__global__ __launch_bounds__(1024) void mask_convert(const void* __restrict__ mraw,
                                                     float* __restrict__ maskF) {
  __shared__ u32 orv;
  const int t = threadIdx.x;
  if (t == 0) orv = 0u;
  __syncthreads();
  u32 o = ((const u32*)mraw)[t];
#pragma unroll
  for (int m = 1; m <= 32; m <<= 1) o |= __shfl_xor(o, m);
  if ((t & 63) == 0) atomicOr(&orv, o);
  __syncthreads();
  const u32 orall = orv;
  int mode;                                  // 0=int32, 1=uint8, 2=bf16, 3=fp32
  if ((orall & ~0x01010101u) == 0u) mode = (orall <= 1u) ? 0 : 1;
  else if (orall & 0x0000FF80u)     mode = 2;
  else                              mode = 3;
  const float NEGINF = -__builtin_inff();
#pragma unroll
  for (int i = t; i < 4096; i += 1024) {
    bool mm;
    if      (mode == 0) mm = ((const int*)mraw)[i] != 0;
    else if (mode == 1) mm = ((const unsigned char*)mraw)[i] != 0;
    else if (mode == 2) mm = ((const u16*)mraw)[i] != 0;
    else                mm = ((const float*)mraw)[i] != 0.f;
    maskF[i] = mm ? NEGINF : 0.f;
  }
}

// ---------------------------------------------------------------------------
// Adaptive-dtype -> bf16 convert for BOTH inputs in one launch. grid = 4096.
// Blocks 0..2047 -> query (4M elems), 2048..4095 -> key_value (4M elems).
// ---------------------------------------------------------------------------
__global__ __launch_bounds__(256) void to_bf16_2(const void* __restrict__ q, const void* __restrict__ kv,
                                                 const int* __restrict__ flag,
                                                 u16* __restrict__ outq, u16* __restrict__ outkv) {
  const int f32 = flag[0];
  if (blockIdx.x < 2048) {
    const size_t idx = ((size_t)blockIdx.x*256 + threadIdx.x)*8;
    *(uint4*)(outq + idx) = ld8(q, idx, f32);
  } else {
    const size_t idx = ((size_t)(blockIdx.x - 2048)*256 + threadIdx.x)*8;
    *(uint4*)(outkv + idx) = ld8(kv, idx, f32);
  }
}

// ---------------------------------------------------------------------------
// Adaptive-input transpose: in[R][C] (fp32 or bf16) -> out[C][R] bf16.
// ---------------------------------------------------------------------------
__global__ __launch_bounds__(256) void transpose_w(const void* __restrict__ in, const int* __restrict__ flag,
                                                   u16* __restrict__ out, int R, int C) {
  __shared__ u16 tile[64][72];
  const int f32 = flag[0];
  const int t = threadIdx.x;
  const int c0 = blockIdx.x*64, r0 = blockIdx.y*64;
  const int lr = t >> 2, cs = (t & 3)*16;
#pragma unroll
  for (int i=0;i<2;i++)
    *(uint4*)&tile[lr][cs + i*8] = ld8(in, (size_t)(r0 + lr)*C + c0 + cs + i*8, f32);
  __syncthreads();
  const int c = t >> 2, rs = (t & 3)*16;
  u16 v[16];
#pragma unroll
  for (int j=0;j<16;j++) v[j] = tile[rs + j][c];
  uint4 u0 = { pk(v[0],v[1]), pk(v[2],v[3]), pk(v[4],v[5]), pk(v[6],v[7]) };
  uint4 u1 = { pk(v[8],v[9]), pk(v[10],v[11]), pk(v[12],v[13]), pk(v[14],v[15]) };
  u16* op = out + (size_t)(c0 + c)*R + r0 + rs;
  *(uint4*)op = u0;
  *(uint4*)(op + 8) = u1;
}

// ---------------------------------------------------------------------------
// NT GEMM: C[M][N] = A[M][K] @ Bt[N][K]^T + bias[N]. A/Bt/C bf16, fp32 accum.
// 128x128 tile, BK=64, global_load_lds width-16 into DOUBLE-BUFFERED linear
// LDS (2-phase: issue next tile's loads BEFORE computing current; single
// __syncthreads per K-step drains vmcnt). grid = (N/128, M/128).
// ---------------------------------------------------------------------------
__global__ __launch_bounds__(256) void gemm_nt(const u16* __restrict__ A, const u16* __restrict__ Bt,
                                               const void* __restrict__ bias, const int* __restrict__ flag,
                                               u16* __restrict__ C, int Mdim, int Ndim, int Kdim) {
  __shared__ u16 As[2][128][64];
  __shared__ u16 Bs[2][128][64];
  const int f32 = flag[0];
  const int tid = threadIdx.x, l = tid & 63, w = tid >> 6;
  const int n0 = blockIdx.x * 128, m0 = blockIdx.y * 128;
  const int wr = (w & 1) * 64, wc = (w >> 1) * 64;
  const int lr = l & 15, lg = l >> 4;
  f32x4 acc[4][4];
#pragma unroll
  for (int i=0;i<4;i++)
#pragma unroll
    for (int j=0;j<4;j++) acc[i][j] = (f32x4){0.f,0.f,0.f,0.f};
  const int srow = l >> 3;          // row within the 8-row segment
  const int scol = (l & 7) * 8;     // element column
  const u16* Ab = A  + (size_t)m0 * Kdim;
  const u16* Bb = Bt + (size_t)n0 * Kdim;
  const int nt = Kdim >> 6;
  // prologue: stage tile 0 into buffer 0
#pragma unroll
  for (int i = 0; i < 4; i++) {
    const int seg = i*4 + w;
    stage16(Ab + (size_t)(seg*8 + srow)*Kdim + scol, &As[0][seg*8][0]);
    stage16(Bb + (size_t)(seg*8 + srow)*Kdim + scol, &Bs[0][seg*8][0]);
  }
  __syncthreads();                  // vmcnt(0) drain: tile 0 in LDS
  for (int t = 0; t < nt; t++) {
    const int pp = t & 1;
    if (t + 1 < nt) {
      const int k1 = (t + 1) << 6;
#pragma unroll
      for (int i = 0; i < 4; i++) {
        const int seg = i*4 + w;
        stage16(Ab + (size_t)(seg*8 + srow)*Kdim + k1 + scol, &As[pp^1][seg*8][0]);
        stage16(Bb + (size_t)(seg*8 + srow)*Kdim + k1 + scol, &Bs[pp^1][seg*8][0]);
      }
    }
    bf16x8 af[4][2], bfr[4][2];
#pragma unroll
    for (int rt=0; rt<4; rt++) {
      af[rt][0] = ldf(&As[pp][wr + rt*16 + lr][lg*8]);
      af[rt][1] = ldf(&As[pp][wr + rt*16 + lr][32 + lg*8]);
    }
#pragma unroll
    for (int ct=0; ct<4; ct++) {
      bfr[ct][0] = ldf(&Bs[pp][wc + ct*16 + lr][lg*8]);
      bfr[ct][1] = ldf(&Bs[pp][wc + ct*16 + lr][32 + lg*8]);
    }
#pragma unroll
    for (int rt=0; rt<4; rt++)
#pragma unroll
      for (int ct=0; ct<4; ct++) {
        acc[rt][ct] = MFMA16(af[rt][0], bfr[ct][0], acc[rt][ct], 0,0,0);
        acc[rt][ct] = MFMA16(af[rt][1], bfr[ct][1], acc[rt][ct], 0,0,0);
      }
    __syncthreads();                // drains vmcnt (next tile landed) + lgkm
  }
#pragma unroll
  for (int ct=0; ct<4; ct++) {
    const int col = n0 + wc + ct*16 + lr;
    const float bv = lds1(bias, col, f32);
#pragma unroll
    for (int rt=0; rt<4; rt++)
#pragma unroll
      for (int r=0; r<4; r++) {
        const int row = m0 + wr + rt*16 + lg*4 + r;
        C[(size_t)row * Ndim + col] = f2b(acc[rt][ct][r] + bv);
      }
  }
}

// ---------------------------------------------------------------------------
// Extract V from KV buffer and transpose per head: Vt[b][h][hd][m].
// grid = (M/64, H, B).
// ---------------------------------------------------------------------------
__global__ __launch_bounds__(256) void build_vt(const u16* __restrict__ KVb, u16* __restrict__ Vt) {
  __shared__ u16 tile[64][72];
  const int t = threadIdx.x;
  const int m0 = blockIdx.x*64, h = blockIdx.y, b = blockIdx.z;
  const int mr = t >> 2, cs = (t & 3)*16;
  const u16* src = KVb + (size_t)(b*1024 + m0 + mr)*2048 + 1024 + h*64;
#pragma unroll
  for (int i=0;i<2;i++)
    *(uint4*)&tile[mr][cs + i*8] = *(const uint4*)(src + cs + i*8);
  __syncthreads();
  const int hd = t >> 2, ms = (t & 3)*16;
  u16 v[16];
#pragma unroll
  for (int j=0;j<16;j++) v[j] = tile[ms + j][hd];
  uint4 u0 = { pk(v[0],v[1]), pk(v[2],v[3]), pk(v[4],v[5]), pk(v[6],v[7]) };
  uint4 u1 = { pk(v[8],v[9]), pk(v[10],v[11]), pk(v[12],v[13]), pk(v[14],v[15]) };
  u16* op = Vt + (size_t)((b*16 + h)*64 + hd)*1024 + m0 + ms;
  *(uint4*)op = u0;
  *(uint4*)(op + 8) = u1;
}

// ---------------------------------------------------------------------------
// SINGLE-PASS flash attention per (n-tile=64, h, b). One loop over M (chunk=128):
// online max/sum, O rescaled by alpha. T14 async-STAGE: chunk c+1's K/V/mask
// prefetched into REGISTERS while chunk c computes; ds_write at next iter top.
// P stored UNNORMALIZED to Pbuf as exp2(s - m_running_c) (<= 1, bf16-safe);
// per-chunk running max -> Sc, final {m_fin, 1/l} -> Fin.
// exp2 args clamped via fmaxf(x,-1000) (IEEE maxNum drops NaN/-inf).
// ---------------------------------------------------------------------------
__global__ __launch_bounds__(256) void attn_kern(const u16* __restrict__ Qb, const u16* __restrict__ KVb,
                                                 const u16* __restrict__ Vt, const float* __restrict__ maskF,
                                                 u16* __restrict__ Pbuf, u16* __restrict__ Obuf,
                                                 float* __restrict__ Sc, float* __restrict__ Fin) {
  __shared__ u16 Ks[128][72];
  __shared__ u16 Vts[64][136];
  __shared__ u16 Ps[4][16][136];
  __shared__ float mlds[128];
  const int tid = threadIdx.x, l = tid & 63, w = tid >> 6;
  const int lr = l & 15, lg = l >> 4;
  const int n0 = blockIdx.x * 64, h = blockIdx.y, b = blockIdx.z;
  const float NEGINF = -__builtin_inff();
  const float scale2 = 0.125f * 1.44269504088896f;  // HD^-0.5 * log2(e)

  bf16x8 qf[2];
  {
    const u16* Qsrc = Qb + (size_t)(b*1024 + n0 + 16*w + lr)*1024 + h*64 + lg*8;
    qf[0] = ldf(Qsrc);
    qf[1] = ldf(Qsrc + 32);
  }
  float mrow[4] = {NEGINF,NEGINF,NEGINF,NEGINF};
  float lrow[4] = {0.f,0.f,0.f,0.f};
  f32x4 oacc[4];
#pragma unroll
  for (int vt=0; vt<4; vt++) oacc[vt] = (f32x4){0.f,0.f,0.f,0.f};

  const int ksr = tid >> 1, kss = (tid & 1)*32;
  const u16* Kbase = KVb + (size_t)(b*1024)*2048 + h*64;
  const u16* Vbase = Vt + (size_t)((b*16 + h)*64)*1024;
  const int vsr = tid >> 2, vss = (tid & 3)*32;

  // prefetch chunk 0 into registers
  uint4 kreg[4], vreg[4];
  float mreg;
#pragma unroll
  for (int i=0;i<4;i++) {
    kreg[i] = *(const uint4*)(Kbase + (size_t)ksr*2048 + kss + i*8);
    vreg[i] = *(const uint4*)(Vbase + (size_t)vsr*1024 + vss + i*8);
  }
  mreg = (tid < 128) ? maskF[b*1024 + tid] : 0.f;

  for (int c = 0; c < 8; c++) {
    __syncthreads();               // prev chunk's LDS reads drained (lgkm)
#pragma unroll
    for (int i=0;i<4;i++) {
      *(uint4*)&Ks[ksr][kss + i*8] = kreg[i];
      *(uint4*)&Vts[vsr][vss + i*8] = vreg[i];
    }
    if (tid < 128) mlds[tid] = mreg;
    __syncthreads();
    // issue next chunk's global loads (hide latency under this chunk's compute)
    if (c < 7) {
      const int m1 = (c + 1) * 128;
#pragma unroll
      for (int i=0;i<4;i++) {
        kreg[i] = *(const uint4*)(Kbase + (size_t)(m1 + ksr)*2048 + kss + i*8);
        vreg[i] = *(const uint4*)(Vbase + (size_t)vsr*1024 + m1 + vss + i*8);
      }
      mreg = (tid < 128) ? maskF[b*1024 + m1 + tid] : 0.f;
    }
    // QK^T for this chunk
    f32x4 sa[8];
#pragma unroll
    for (int ct=0; ct<8; ct++) {
      sa[ct] = (f32x4){0.f,0.f,0.f,0.f};
      bf16x8 k0 = ldf(&Ks[ct*16 + lr][lg*8]);
      bf16x8 k1 = ldf(&Ks[ct*16 + lr][32 + lg*8]);
      sa[ct] = MFMA16(qf[0], k0, sa[ct], 0,0,0);
      sa[ct] = MFMA16(qf[1], k1, sa[ct], 0,0,0);
    }
    // scale + mask + chunk max
    float cmax[4] = {NEGINF,NEGINF,NEGINF,NEGINF};
#pragma unroll
    for (int ct=0; ct<8; ct++) {
      const float mv = mlds[ct*16 + lr];
#pragma unroll
      for (int r=0;r<4;r++) {
        float s = fmaf(sa[ct][r], scale2, mv);
        sa[ct][r] = s;
        cmax[r] = fmaxf(cmax[r], s);
      }
    }
    // online softmax update; sa becomes p = exp2(s - m_new)
    float al[4];
#pragma unroll
    for (int r=0;r<4;r++) {
#pragma unroll
      for (int m = 1; m <= 8; m <<= 1) cmax[r] = fmaxf(cmax[r], __shfl_xor(cmax[r], m));
      const float mnew = fmaxf(mrow[r], cmax[r]);
      al[r] = exp2f(fmaxf(mrow[r] - mnew, -1000.f));
      float se = 0.f;
#pragma unroll
      for (int ct=0; ct<8; ct++) {
        float p = exp2f(fmaxf(sa[ct][r] - mnew, -1000.f));
        sa[ct][r] = p;
        se += p;
      }
#pragma unroll
      for (int m = 1; m <= 8; m <<= 1) se += __shfl_xor(se, m);
      lrow[r] = lrow[r] * al[r] + se;
      mrow[r] = mnew;
      if (lr == 0)
        Sc[(((size_t)b*1024 + n0 + 16*w + lg*4 + r)*16 + h)*8 + c] = mnew;
    }
    // P (unnormalized) -> LDS, then coalesced to Pbuf
#pragma unroll
    for (int ct=0; ct<8; ct++)
#pragma unroll
      for (int r=0;r<4;r++)
        Ps[w][lg*4 + r][ct*16 + lr] = f2b(sa[ct][r]);
    {
      const int pr = l >> 2, psg = (l & 3) * 32;
      u16* gp = Pbuf + (size_t)((b*16 + h)*1024 + n0 + 16*w + pr)*1024 + c*128 + psg;
#pragma unroll
      for (int i=0;i<4;i++)
        *(uint4*)(gp + i*8) = *(const uint4*)&Ps[w][pr][psg + i*8];
    }
    // rescale O by alpha, then accumulate P.V
#pragma unroll
    for (int vt=0; vt<4; vt++)
#pragma unroll
      for (int r=0;r<4;r++) oacc[vt][r] *= al[r];
    bf16x8 pa[4];
#pragma unroll
    for (int t=0;t<4;t++) pa[t] = ldf(&Ps[w][lr][t*32 + lg*8]);
#pragma unroll
    for (int vt=0; vt<4; vt++) {
#pragma unroll
      for (int t=0;t<4;t++) {
        bf16x8 bv = ldf(&Vts[vt*16 + lr][t*32 + lg*8]);
        oacc[vt] = MFMA16(pa[t], bv, oacc[vt], 0,0,0);
      }
    }
  }
  // epilogue: normalize O, store per-row finals
  float rinv[4];
#pragma unroll
  for (int r=0;r<4;r++) rinv[r] = (lrow[r] > 0.f) ? 1.f / lrow[r] : 0.f;
#pragma unroll
  for (int vt=0; vt<4; vt++)
#pragma unroll
    for (int r=0;r<4;r++) {
      const int row = b*1024 + n0 + 16*w + lg*4 + r;
      const int col = h*64 + vt*16 + lr;
      Obuf[(size_t)row*1024 + col] = f2b(oacc[vt][r] * rinv[r]);
    }
  if (lr == 0) {
#pragma unroll
    for (int r=0;r<4;r++) {
      const size_t fo = (((size_t)b*1024 + n0 + 16*w + lg*4 + r)*16 + h)*2;
      Fin[fo]   = mrow[r];
      Fin[fo+1] = rinv[r];
    }
  }
}

// ---------------------------------------------------------------------------
// Permute Pbuf[b][h][n][m] -> attention[b][n][m][h] as FP32, applying the
// deferred normalization scale[h][c] = exp2(m_c - m_fin) * rinv. grid = (N, B).
// ---------------------------------------------------------------------------
__global__ __launch_bounds__(256) void transpose_p(const u16* __restrict__ Pbuf,
                                                   const float* __restrict__ Sc,
                                                   const float* __restrict__ Fin,
                                                   float* __restrict__ out) {
  __shared__ u16 t2[16][1024];
  __shared__ float slut[128];    // [h][c]
  const int t = threadIdx.x;
  const int n = blockIdx.x, b = blockIdx.y;
  const int h = t >> 4, sg = (t & 15)*64;
  const u16* src = Pbuf + (size_t)((b*16 + h)*1024 + n)*1024 + sg;
#pragma unroll
  for (int i=0;i<8;i++)
    *(uint4*)&t2[h][sg + i*8] = *(const uint4*)(src + i*8);
  if (t < 128) {
    const int hh = t >> 3, cc = t & 7;
    const size_t base = ((size_t)b*1024 + n)*16 + hh;
    const float mc = Sc[base*8 + cc];
    const float mf = Fin[base*2];
    const float ri = Fin[base*2 + 1];
    slut[t] = exp2f(fmaxf(mc - mf, -1000.f)) * ri;
  }
  __syncthreads();
  float* dst = out + (size_t)(b*1024 + n)*16384;
#pragma unroll
  for (int mi=0; mi<4; mi++) {
    const int m = t + mi*256;
    const int c = m >> 7;
#pragma unroll
    for (int q=0; q<4; q++) {
      f32x4 v;
#pragma unroll
      for (int j=0; j<4; j++) v[j] = b2f(t2[q*4 + j][m]) * slut[(q*4 + j)*8 + c];
      *(f32x4*)(dst + (size_t)m*16 + q*4) = v;
    }
  }
}

// ---------------------------------------------------------------------------
// out0[row][0:2] = Obuf[row][:] @ Wp + bp (fp32 out). grid = 1024.
// ---------------------------------------------------------------------------
__global__ __launch_bounds__(256) void proj_out_k(const u16* __restrict__ Obuf, const void* __restrict__ Wp,
                                                  const void* __restrict__ bp, const int* __restrict__ flag,
                                                  float* __restrict__ out0) {
  const int f32 = flag[0];
  const int l = threadIdx.x & 63, w = threadIdx.x >> 6;
  const int row = blockIdx.x*4 + w;
  const u16* op = Obuf + (size_t)row*1024 + l*16;
  float d0 = 0.f, d1 = 0.f;
#pragma unroll
  for (int j=0;j<16;j++) {
    const float o = b2f(op[j]);
    d0 = fmaf(o, lds1(Wp, (size_t)(l*16 + j)*2,     f32), d0);
    d1 = fmaf(o, lds1(Wp, (size_t)(l*16 + j)*2 + 1, f32), d1);
  }
#pragma unroll
  for (int m=1; m<=32; m<<=1) { d0 += __shfl_xor(d0, m); d1 += __shfl_xor(d1, m); }
  if (l == 0) {
    out0[row*2]   = d0 + lds1(bp, 0, f32);
    out0[row*2+1] = d1 + lds1(bp, 1, f32);
  }
}

extern "C" void kernel_launch(void* const* d_in, const int* in_sizes, int n_in,
                              void* d_out, int out_size, void* d_ws, size_t ws_size,
                              hipStream_t stream) {
  const void* query     = d_in[0];
  const void* key_value = d_in[1];
  const void* mask      = d_in[2];
  const void* Wq        = d_in[3];
  const void* bq        = d_in[4];
  const void* Wkv       = d_in[5];
  const void* bkv       = d_in[6];
  const void* Wp        = d_in[7];
  const void* bp        = d_in[8];
  float* out0     = (float*)d_out;            // (4,1024,2) fp32
  float* attn_out = (float*)d_out + 8192;     // (4,1024,1024,16) fp32

  char* ws = (char*)d_ws;
  u16*   WqT   = (u16*)(ws);                        // 2 MiB
  u16*   WkvT  = (u16*)(ws + (2u<<20));             // 4 MiB
  u16*   Qb    = (u16*)(ws + (6u<<20));             // 8 MiB
  u16*   KVb   = (u16*)(ws + (14u<<20));            // 16 MiB
  u16*   Vt    = (u16*)(ws + (30u<<20));            // 8 MiB
  u16*   Obuf  = (u16*)(ws + (38u<<20));            // 8 MiB  (38..46)
  float* maskF = (float*)(ws + (46u<<20));          // 16 KiB (after Obuf!)
  int*   flag  = (int*)(ws + (46u<<20) + 16384);    // 4 B
  u16*   Pbuf  = (u16*)(ws + (47u<<20));            // 128 MiB (47..175)
  float* Sc    = (float*)(ws + (175u<<20));         // 2 MiB   [b][n][h][c] running max
  float* Fin   = (float*)(ws + (177u<<20));         // 512 KiB [b][n][h][{m_fin,rinv}]
  // Converted bf16 inputs alias the FIRST 16 MiB of the Pbuf region: they are
  // dead before attn_kern (the only Pbuf writer) launches. No extra ws needed.
  u16*   Qc    = (u16*)(ws + (47u<<20));            // 8 MiB  (alias Pbuf+0)
  u16*   KVc   = (u16*)(ws + (55u<<20));            // 8 MiB  (alias Pbuf+8M)

  detect_dtype<<<1, 256, 0, stream>>>((const u32*)query, flag);
  mask_convert<<<1, 1024, 0, stream>>>(mask, maskF);
  to_bf16_2<<<4096, 256, 0, stream>>>(query, key_value, flag, Qc, KVc);
  transpose_w<<<dim3(16,16), 256, 0, stream>>>(Wq, flag, WqT, 1024, 1024);
  transpose_w<<<dim3(32,16), 256, 0, stream>>>(Wkv, flag, WkvT, 1024, 2048);
  gemm_nt<<<dim3(8,32),  256, 0, stream>>>(Qc,  WqT,  bq,  flag, Qb,  4096, 1024, 1024);
  gemm_nt<<<dim3(16,32), 256, 0, stream>>>(KVc, WkvT, bkv, flag, KVb, 4096, 2048, 1024);
  build_vt<<<dim3(16,16,4), 256, 0, stream>>>(KVb, Vt);
  attn_kern<<<dim3(16,16,4), 256, 0, stream>>>(Qb, KVb, Vt, maskF, Pbuf, Obuf, Sc, Fin);
  transpose_p<<<dim3(1024,4), 256, 0, stream>>>(Pbuf, Sc, Fin, attn_out);
  proj_out_k<<<dim3(1024), 256, 0, stream>>>(Obuf, Wp, bp, flag, out0);
}

// Round 6
// 518.895 us; speedup vs baseline: 1.1481x; 1.1481x over previous
//
#include <hip/hip_runtime.h>

typedef unsigned short u16;
typedef unsigned int u32;
typedef __bf16 bf16x8 __attribute__((ext_vector_type(8)));
typedef float f32x4 __attribute__((ext_vector_type(4)));

#define MFMA16 __builtin_amdgcn_mfma_f32_16x16x32_bf16

// B=4, N=1024, M=1024, D=1024, KV=1024, H=16, HD=64
// Interface dtypes per harness contract: inputs fp32 (detector hedges bf16),
// mask int32 (detector hedges u8/bf16/fp32), outputs fp32.

__device__ __forceinline__ float b2f(u16 u){ u32 x = ((u32)u)<<16; float f; __builtin_memcpy(&f,&x,4); return f; }
__device__ __forceinline__ u16 f2b(float f){ u32 x; __builtin_memcpy(&x,&f,4); return (u16)((x + 0x7fffu + ((x>>16)&1u)) >> 16); }
__device__ __forceinline__ bf16x8 ldf(const u16* p){ uint4 v = *(const uint4*)p; return __builtin_bit_cast(bf16x8, v); }
__device__ __forceinline__ u32 pk(u16 a, u16 b){ return (u32)a | ((u32)b<<16); }

// Async global->LDS: 16B per lane, dest = wave-uniform base + lane*16 (m97 pattern).
__device__ __forceinline__ void stage16(const u16* g, u16* l) {
  __builtin_amdgcn_global_load_lds(
      (const __attribute__((address_space(1))) void*)g,
      (__attribute__((address_space(3))) void*)l, 16, 0, 0);
}

// Load 8 consecutive logical elements of a float input as packed bf16 (uint4).
__device__ __forceinline__ uint4 ld8(const void* base, size_t off, int f32) {
  if (f32) {
    const float* p = (const float*)base + off;
    f32x4 a = *(const f32x4*)p;
    f32x4 b = *(const f32x4*)(p + 4);
    uint4 r;
    r.x = pk(f2b(a[0]), f2b(a[1]));
    r.y = pk(f2b(a[2]), f2b(a[3]));
    r.z = pk(f2b(b[0]), f2b(b[1]));
    r.w = pk(f2b(b[2]), f2b(b[3]));
    return r;
  }
  return *(const uint4*)((const u16*)base + off);
}
__device__ __forceinline__ float lds1(const void* base, size_t off, int f32) {
  return f32 ? ((const float*)base)[off] : b2f(((const u16*)base)[off]);
}

// ---------------------------------------------------------------------------
// Fused prep: block 0 = input dtype detection (flag: 1=fp32, 0=bf16);
// block 1 = mask dtype detection + conversion to float {0,-inf}. grid = 2.
// ---------------------------------------------------------------------------
__global__ __launch_bounds__(256) void fused_prep(const u32* __restrict__ q, const void* __restrict__ mraw,
                                                  int* __restrict__ flag, float* __restrict__ maskF) {
  const int t = threadIdx.x;
  if (blockIdx.x == 0) {
    __shared__ int cnt;
    if (t == 0) cnt = 0;
    __syncthreads();
    int c = 0;
#pragma unroll
    for (int i = 0; i < 4; i++) {
      u32 w = q[t + i*256];
      u32 e = (w >> 7) & 0xFFu;
      c += (e >= 100u && e <= 140u) ? 1 : 0;
    }
#pragma unroll
    for (int m = 1; m <= 32; m <<= 1) c += __shfl_xor(c, m);
    if ((t & 63) == 0) atomicAdd(&cnt, c);
    __syncthreads();
    if (t == 0) flag[0] = (cnt < 512) ? 1 : 0;
  } else {
    __shared__ u32 orv;
    if (t == 0) orv = 0u;
    __syncthreads();
    u32 o = 0u;
#pragma unroll
    for (int i = 0; i < 4; i++) o |= ((const u32*)mraw)[t + i*256];
#pragma unroll
    for (int m = 1; m <= 32; m <<= 1) o |= __shfl_xor(o, m);
    if ((t & 63) == 0) atomicOr(&orv, o);
    __syncthreads();
    const u32 orall = orv;
    int mode;                                // 0=int32, 1=uint8, 2=bf16, 3=fp32
    if ((orall & ~0x01010101u) == 0u) mode = (orall <= 1u) ? 0 : 1;
    else if (orall & 0x0000FF80u)     mode = 2;
    else                              mode = 3;
    const float NEGINF = -__builtin_inff();
    for (int i = t; i < 4096; i += 256) {
      bool mm;
      if      (mode == 0) mm = ((const int*)mraw)[i] != 0;
      else if (mode == 1) mm = ((const unsigned char*)mraw)[i] != 0;
      else if (mode == 2) mm = ((const u16*)mraw)[i] != 0;
      else                mm = ((const float*)mraw)[i] != 0.f;
      maskF[i] = mm ? NEGINF : 0.f;
    }
  }
}

// ---------------------------------------------------------------------------
// Adaptive-dtype -> bf16 convert for BOTH inputs in one launch. grid = 4096.
// ---------------------------------------------------------------------------
__global__ __launch_bounds__(256) void to_bf16_2(const void* __restrict__ q, const void* __restrict__ kv,
                                                 const int* __restrict__ flag,
                                                 u16* __restrict__ outq, u16* __restrict__ outkv) {
  const int f32 = flag[0];
  if (blockIdx.x < 2048) {
    const size_t idx = ((size_t)blockIdx.x*256 + threadIdx.x)*8;
    *(uint4*)(outq + idx) = ld8(q, idx, f32);
  } else {
    const size_t idx = ((size_t)(blockIdx.x - 2048)*256 + threadIdx.x)*8;
    *(uint4*)(outkv + idx) = ld8(kv, idx, f32);
  }
}

// ---------------------------------------------------------------------------
// Adaptive-input transpose body: in[R][C] -> out[C][R] bf16.
// ---------------------------------------------------------------------------
__device__ __forceinline__ void transpose_w_body(const void* in, int f32, u16* out,
                                                 int R, int C, int bx, int by) {
  __shared__ u16 tile[64][72];
  const int t = threadIdx.x;
  const int c0 = bx*64, r0 = by*64;
  const int lr = t >> 2, cs = (t & 3)*16;
#pragma unroll
  for (int i=0;i<2;i++)
    *(uint4*)&tile[lr][cs + i*8] = ld8(in, (size_t)(r0 + lr)*C + c0 + cs + i*8, f32);
  __syncthreads();
  const int c = t >> 2, rs = (t & 3)*16;
  u16 v[16];
#pragma unroll
  for (int j=0;j<16;j++) v[j] = tile[rs + j][c];
  uint4 u0 = { pk(v[0],v[1]), pk(v[2],v[3]), pk(v[4],v[5]), pk(v[6],v[7]) };
  uint4 u1 = { pk(v[8],v[9]), pk(v[10],v[11]), pk(v[12],v[13]), pk(v[14],v[15]) };
  u16* op = out + (size_t)(c0 + c)*R + r0 + rs;
  *(uint4*)op = u0;
  *(uint4*)(op + 8) = u1;
}

// Both weight transposes in one launch. grid = (48,16): x<16 -> Wq, else Wkv.
__global__ __launch_bounds__(256) void transpose_w2(const void* __restrict__ Wq, const void* __restrict__ Wkv,
                                                    const int* __restrict__ flag,
                                                    u16* __restrict__ WqT, u16* __restrict__ WkvT) {
  const int f32 = flag[0];
  if (blockIdx.x < 16) transpose_w_body(Wq,  f32, WqT,  1024, 1024, blockIdx.x,      blockIdx.y);
  else                 transpose_w_body(Wkv, f32, WkvT, 1024, 2048, blockIdx.x - 16, blockIdx.y);
}

// ---------------------------------------------------------------------------
// NT GEMM body (m97 structure): C[.][N] = A[.][K] @ Bt[N][K]^T + bias[N].
// 128x128 tile, BK=64, global_load_lds width-16 into LINEAR single-buffer LDS.
// ---------------------------------------------------------------------------
__device__ __forceinline__ void gemm_body(const u16* A, const u16* Bt, const void* bias, int f32,
                                          u16* C, int Ndim, int Kdim, int bx, int by) {
  __shared__ u16 As[128][64];
  __shared__ u16 Bs[128][64];
  const int tid = threadIdx.x, l = tid & 63, w = tid >> 6;
  const int n0 = bx * 128, m0 = by * 128;
  const int wr = (w & 1) * 64, wc = (w >> 1) * 64;
  const int lr = l & 15, lg = l >> 4;
  f32x4 acc[4][4];
#pragma unroll
  for (int i=0;i<4;i++)
#pragma unroll
    for (int j=0;j<4;j++) acc[i][j] = (f32x4){0.f,0.f,0.f,0.f};
  const int srow = l >> 3;          // row within the 8-row segment
  const int scol = (l & 7) * 8;     // element column
  const u16* Ab = A  + (size_t)m0 * Kdim;
  const u16* Bb = Bt + (size_t)n0 * Kdim;
  for (int k0 = 0; k0 < Kdim; k0 += 64) {
    __syncthreads();
#pragma unroll
    for (int i = 0; i < 4; i++) {
      const int seg = i*4 + w;      // 0..15, wave-uniform
      stage16(Ab + (size_t)(seg*8 + srow)*Kdim + k0 + scol, &As[seg*8][0]);
      stage16(Bb + (size_t)(seg*8 + srow)*Kdim + k0 + scol, &Bs[seg*8][0]);
    }
    __syncthreads();               // compiler drains vmcnt(0) before s_barrier
    bf16x8 af[4][2], bfr[4][2];
#pragma unroll
    for (int rt=0; rt<4; rt++) {
      af[rt][0] = ldf(&As[wr + rt*16 + lr][lg*8]);
      af[rt][1] = ldf(&As[wr + rt*16 + lr][32 + lg*8]);
    }
#pragma unroll
    for (int ct=0; ct<4; ct++) {
      bfr[ct][0] = ldf(&Bs[wc + ct*16 + lr][lg*8]);
      bfr[ct][1] = ldf(&Bs[wc + ct*16 + lr][32 + lg*8]);
    }
#pragma unroll
    for (int rt=0; rt<4; rt++)
#pragma unroll
      for (int ct=0; ct<4; ct++) {
        acc[rt][ct] = MFMA16(af[rt][0], bfr[ct][0], acc[rt][ct], 0,0,0);
        acc[rt][ct] = MFMA16(af[rt][1], bfr[ct][1], acc[rt][ct], 0,0,0);
      }
  }
#pragma unroll
  for (int ct=0; ct<4; ct++) {
    const int col = n0 + wc + ct*16 + lr;
    const float bv = lds1(bias, col, f32);
#pragma unroll
    for (int rt=0; rt<4; rt++)
#pragma unroll
      for (int r=0; r<4; r++) {
        const int row = m0 + wr + rt*16 + lg*4 + r;
        C[(size_t)row * Ndim + col] = f2b(acc[rt][ct][r] + bv);
      }
  }
}

// Both projections in one launch (fills machine: 768 blocks). grid = (24,32).
// x<8 -> Q gemm (N=1024), x>=8 -> KV gemm (N=2048). Rows = 4096 both.
__global__ __launch_bounds__(256) void gemm_fused(const u16* __restrict__ Qc, const u16* __restrict__ WqT,
                                                  const void* __restrict__ bq,
                                                  const u16* __restrict__ KVc, const u16* __restrict__ WkvT,
                                                  const void* __restrict__ bkv,
                                                  const int* __restrict__ flag,
                                                  u16* __restrict__ Qb, u16* __restrict__ KVb) {
  const int f32 = flag[0];
  const bool isQ = blockIdx.x < 8;
  const u16* A    = isQ ? Qc  : KVc;
  const u16* Bt   = isQ ? WqT : WkvT;
  const void* bia = isQ ? bq  : bkv;
  u16* C          = isQ ? Qb  : KVb;
  const int Ndim  = isQ ? 1024 : 2048;
  const int bx    = isQ ? blockIdx.x : blockIdx.x - 8;
  gemm_body(A, Bt, bia, f32, C, Ndim, 1024, bx, blockIdx.y);
}

// ---------------------------------------------------------------------------
// Extract V from KV buffer and transpose per head: Vt[b][h][hd][m].
// grid = (M/64, H, B).
// ---------------------------------------------------------------------------
__global__ __launch_bounds__(256) void build_vt(const u16* __restrict__ KVb, u16* __restrict__ Vt) {
  __shared__ u16 tile[64][72];
  const int t = threadIdx.x;
  const int m0 = blockIdx.x*64, h = blockIdx.y, b = blockIdx.z;
  const int mr = t >> 2, cs = (t & 3)*16;
  const u16* src = KVb + (size_t)(b*1024 + m0 + mr)*2048 + 1024 + h*64;
#pragma unroll
  for (int i=0;i<2;i++)
    *(uint4*)&tile[mr][cs + i*8] = *(const uint4*)(src + cs + i*8);
  __syncthreads();
  const int hd = t >> 2, ms = (t & 3)*16;
  u16 v[16];
#pragma unroll
  for (int j=0;j<16;j++) v[j] = tile[ms + j][hd];
  uint4 u0 = { pk(v[0],v[1]), pk(v[2],v[3]), pk(v[4],v[5]), pk(v[6],v[7]) };
  uint4 u1 = { pk(v[8],v[9]), pk(v[10],v[11]), pk(v[12],v[13]), pk(v[14],v[15]) };
  u16* op = Vt + (size_t)((b*16 + h)*64 + hd)*1024 + m0 + ms;
  *(uint4*)op = u0;
  *(uint4*)(op + 8) = u1;
}

// ---------------------------------------------------------------------------
// SINGLE-PASS flash attention per (n-tile=64, h, b). One loop over M (chunk=128):
// online max/sum, O rescaled by alpha. P stored UNNORMALIZED to Pbuf as
// exp2(s - m_running_c) (<= 1, bf16-safe); per-chunk running max m_c -> Sc,
// final {m_fin, 1/l} -> Fin. transpose_p applies exp2(m_c - m_fin)/l.
// exp2 args clamped via fmaxf(x,-1000) (IEEE maxNum drops NaN/-inf).
// ---------------------------------------------------------------------------
__global__ __launch_bounds__(256) void attn_kern(const u16* __restrict__ Qb, const u16* __restrict__ KVb,
                                                 const u16* __restrict__ Vt, const float* __restrict__ maskF,
                                                 u16* __restrict__ Pbuf, u16* __restrict__ Obuf,
                                                 float* __restrict__ Sc, float* __restrict__ Fin) {
  __shared__ u16 Ks[128][72];
  __shared__ u16 Vts[64][136];
  __shared__ u16 Ps[4][16][136];
  __shared__ float mlds[128];
  const int tid = threadIdx.x, l = tid & 63, w = tid >> 6;
  const int lr = l & 15, lg = l >> 4;
  const int n0 = blockIdx.x * 64, h = blockIdx.y, b = blockIdx.z;
  const float NEGINF = -__builtin_inff();
  const float scale2 = 0.125f * 1.44269504088896f;  // HD^-0.5 * log2(e)

  bf16x8 qf[2];
  {
    const u16* Qsrc = Qb + (size_t)(b*1024 + n0 + 16*w + lr)*1024 + h*64 + lg*8;
    qf[0] = ldf(Qsrc);
    qf[1] = ldf(Qsrc + 32);
  }
  float mrow[4] = {NEGINF,NEGINF,NEGINF,NEGINF};
  float lrow[4] = {0.f,0.f,0.f,0.f};
  f32x4 oacc[4];
#pragma unroll
  for (int vt=0; vt<4; vt++) oacc[vt] = (f32x4){0.f,0.f,0.f,0.f};

  const int ksr = tid >> 1, kss = (tid & 1)*32;
  const u16* Kbase = KVb + (size_t)(b*1024)*2048 + h*64;
  const u16* Vbase = Vt + (size_t)((b*16 + h)*64)*1024;
  const int vsr = tid >> 2, vss = (tid & 3)*32;

  for (int c = 0; c < 8; c++) {
    const int m0 = c*128;
    __syncthreads();
#pragma unroll
    for (int i=0;i<4;i++)
      *(uint4*)&Ks[ksr][kss + i*8] = *(const uint4*)(Kbase + (size_t)(m0 + ksr)*2048 + kss + i*8);
#pragma unroll
    for (int i=0;i<4;i++)
      *(uint4*)&Vts[vsr][vss + i*8] = *(const uint4*)(Vbase + (size_t)vsr*1024 + m0 + vss + i*8);
    if (tid < 128) mlds[tid] = maskF[b*1024 + m0 + tid];
    __syncthreads();
    // QK^T for this chunk
    f32x4 sa[8];
#pragma unroll
    for (int ct=0; ct<8; ct++) {
      sa[ct] = (f32x4){0.f,0.f,0.f,0.f};
      bf16x8 k0 = ldf(&Ks[ct*16 + lr][lg*8]);
      bf16x8 k1 = ldf(&Ks[ct*16 + lr][32 + lg*8]);
      sa[ct] = MFMA16(qf[0], k0, sa[ct], 0,0,0);
      sa[ct] = MFMA16(qf[1], k1, sa[ct], 0,0,0);
    }
    // scale + mask + chunk max
    float cmax[4] = {NEGINF,NEGINF,NEGINF,NEGINF};
#pragma unroll
    for (int ct=0; ct<8; ct++) {
      const float mv = mlds[ct*16 + lr];
#pragma unroll
      for (int r=0;r<4;r++) {
        float s = fmaf(sa[ct][r], scale2, mv);
        sa[ct][r] = s;
        cmax[r] = fmaxf(cmax[r], s);
      }
    }
    // online softmax update; sa becomes p = exp2(s - m_new)
    float al[4];
#pragma unroll
    for (int r=0;r<4;r++) {
#pragma unroll
      for (int m = 1; m <= 8; m <<= 1) cmax[r] = fmaxf(cmax[r], __shfl_xor(cmax[r], m));
      const float mnew = fmaxf(mrow[r], cmax[r]);
      al[r] = exp2f(fmaxf(mrow[r] - mnew, -1000.f));
      float se = 0.f;
#pragma unroll
      for (int ct=0; ct<8; ct++) {
        float p = exp2f(fmaxf(sa[ct][r] - mnew, -1000.f));
        sa[ct][r] = p;
        se += p;
      }
#pragma unroll
      for (int m = 1; m <= 8; m <<= 1) se += __shfl_xor(se, m);
      lrow[r] = lrow[r] * al[r] + se;
      mrow[r] = mnew;
      if (lr == 0)
        Sc[(((size_t)b*1024 + n0 + 16*w + lg*4 + r)*16 + h)*8 + c] = mnew;
    }
    // P (unnormalized) -> LDS, then coalesced to Pbuf
#pragma unroll
    for (int ct=0; ct<8; ct++)
#pragma unroll
      for (int r=0;r<4;r++)
        Ps[w][lg*4 + r][ct*16 + lr] = f2b(sa[ct][r]);
    {
      const int pr = l >> 2, psg = (l & 3) * 32;
      u16* gp = Pbuf + (size_t)((b*16 + h)*1024 + n0 + 16*w + pr)*1024 + m0 + psg;
#pragma unroll
      for (int i=0;i<4;i++)
        *(uint4*)(gp + i*8) = *(const uint4*)&Ps[w][pr][psg + i*8];
    }
    // rescale O by alpha, then accumulate P.V
#pragma unroll
    for (int vt=0; vt<4; vt++)
#pragma unroll
      for (int r=0;r<4;r++) oacc[vt][r] *= al[r];
    bf16x8 pa[4];
#pragma unroll
    for (int t=0;t<4;t++) pa[t] = ldf(&Ps[w][lr][t*32 + lg*8]);
#pragma unroll
    for (int vt=0; vt<4; vt++) {
#pragma unroll
      for (int t=0;t<4;t++) {
        bf16x8 bv = ldf(&Vts[vt*16 + lr][t*32 + lg*8]);
        oacc[vt] = MFMA16(pa[t], bv, oacc[vt], 0,0,0);
      }
    }
  }
  // epilogue: normalize O, store per-row finals
  float rinv[4];
#pragma unroll
  for (int r=0;r<4;r++) rinv[r] = (lrow[r] > 0.f) ? 1.f / lrow[r] : 0.f;
#pragma unroll
  for (int vt=0; vt<4; vt++)
#pragma unroll
    for (int r=0;r<4;r++) {
      const int row = b*1024 + n0 + 16*w + lg*4 + r;
      const int col = h*64 + vt*16 + lr;
      Obuf[(size_t)row*1024 + col] = f2b(oacc[vt][r] * rinv[r]);
    }
  if (lr == 0) {
#pragma unroll
    for (int r=0;r<4;r++) {
      const size_t fo = (((size_t)b*1024 + n0 + 16*w + lg*4 + r)*16 + h)*2;
      Fin[fo]   = mrow[r];
      Fin[fo+1] = rinv[r];
    }
  }
}

// ---------------------------------------------------------------------------
// Permute Pbuf[b][h][n][m] -> attention[b][n][m][h] as FP32, applying the
// deferred normalization scale[h][c] = exp2(m_c - m_fin) * rinv. grid = (N, B).
// COALESCED rewrite: reads = 256B-contiguous segments; writes = wave-contiguous
// 1 KiB (lane l covers bytes l*16..+15); LDS tile padded [16][1036] (stride
// 518 dw == 6 mod 32 -> 2 lanes/bank on the read phase = conflict-free).
// ---------------------------------------------------------------------------
__global__ __launch_bounds__(256) void transpose_p(const u16* __restrict__ Pbuf,
                                                   const float* __restrict__ Sc,
                                                   const float* __restrict__ Fin,
                                                   float* __restrict__ out) {
  __shared__ u16 t2[16][1036];
  __shared__ float slut[128];    // [h][c]
  const int t = threadIdx.x;
  const int n = blockIdx.x, b = blockIdx.y;
  const int h = t >> 4, k = t & 15;
  const u16* src = Pbuf + (size_t)((b*16 + h)*1024 + n)*1024;
#pragma unroll
  for (int i=0;i<8;i++)
    *(uint4*)&t2[h][k*8 + i*128] = *(const uint4*)(src + k*8 + i*128);
  if (t < 128) {
    const int hh = t >> 3, cc = t & 7;
    const size_t base = ((size_t)b*1024 + n)*16 + hh;
    const float mc = Sc[base*8 + cc];
    const float mf = Fin[base*2];
    const float ri = Fin[base*2 + 1];
    slut[t] = exp2f(fmaxf(mc - mf, -1000.f)) * ri;
  }
  __syncthreads();
  float* dst = out + (size_t)(b*1024 + n)*16384;
  const int mq = t >> 2, hq = t & 3;     // lane writes h-quad hq of row m
#pragma unroll
  for (int mi=0; mi<16; mi++) {
    const int m = mq + mi*64;
    const int c = m >> 7;
    f32x4 v;
#pragma unroll
    for (int j=0; j<4; j++) {
      const int hh = hq*4 + j;
      v[j] = b2f(t2[hh][m]) * slut[hh*8 + c];
    }
    *(f32x4*)(dst + (size_t)m*16 + hq*4) = v;   // wave: contiguous 1 KiB
  }
}

// ---------------------------------------------------------------------------
// out0[row][0:2] = Obuf[row][:] @ Wp + bp (fp32 out). grid = 1024.
// ---------------------------------------------------------------------------
__global__ __launch_bounds__(256) void proj_out_k(const u16* __restrict__ Obuf, const void* __restrict__ Wp,
                                                  const void* __restrict__ bp, const int* __restrict__ flag,
                                                  float* __restrict__ out0) {
  const int f32 = flag[0];
  const int l = threadIdx.x & 63, w = threadIdx.x >> 6;
  const int row = blockIdx.x*4 + w;
  const u16* op = Obuf + (size_t)row*1024 + l*16;
  float d0 = 0.f, d1 = 0.f;
#pragma unroll
  for (int j=0;j<16;j++) {
    const float o = b2f(op[j]);
    d0 = fmaf(o, lds1(Wp, (size_t)(l*16 + j)*2,     f32), d0);
    d1 = fmaf(o, lds1(Wp, (size_t)(l*16 + j)*2 + 1, f32), d1);
  }
#pragma unroll
  for (int m=1; m<=32; m<<=1) { d0 += __shfl_xor(d0, m); d1 += __shfl_xor(d1, m); }
  if (l == 0) {
    out0[row*2]   = d0 + lds1(bp, 0, f32);
    out0[row*2+1] = d1 + lds1(bp, 1, f32);
  }
}

extern "C" void kernel_launch(void* const* d_in, const int* in_sizes, int n_in,
                              void* d_out, int out_size, void* d_ws, size_t ws_size,
                              hipStream_t stream) {
  const void* query     = d_in[0];
  const void* key_value = d_in[1];
  const void* mask      = d_in[2];
  const void* Wq        = d_in[3];
  const void* bq        = d_in[4];
  const void* Wkv       = d_in[5];
  const void* bkv       = d_in[6];
  const void* Wp        = d_in[7];
  const void* bp        = d_in[8];
  float* out0     = (float*)d_out;            // (4,1024,2) fp32
  float* attn_out = (float*)d_out + 8192;     // (4,1024,1024,16) fp32

  char* ws = (char*)d_ws;
  u16*   WqT   = (u16*)(ws);                        // 2 MiB
  u16*   WkvT  = (u16*)(ws + (2u<<20));             // 4 MiB
  u16*   Qb    = (u16*)(ws + (6u<<20));             // 8 MiB
  u16*   KVb   = (u16*)(ws + (14u<<20));            // 16 MiB
  u16*   Vt    = (u16*)(ws + (30u<<20));            // 8 MiB
  u16*   Obuf  = (u16*)(ws + (38u<<20));            // 8 MiB  (38..46)
  float* maskF = (float*)(ws + (46u<<20));          // 16 KiB (after Obuf!)
  int*   flag  = (int*)(ws + (46u<<20) + 16384);    // 4 B
  u16*   Pbuf  = (u16*)(ws + (47u<<20));            // 128 MiB (47..175)
  float* Sc    = (float*)(ws + (175u<<20));         // 2 MiB   [b][n][h][c] running max
  float* Fin   = (float*)(ws + (177u<<20));         // 512 KiB [b][n][h][{m_fin,rinv}]
  // Converted bf16 inputs alias the FIRST 16 MiB of the Pbuf region: they are
  // dead before attn_kern (the only Pbuf writer) launches. No extra ws needed.
  u16*   Qc    = (u16*)(ws + (47u<<20));            // 8 MiB  (alias Pbuf+0)
  u16*   KVc   = (u16*)(ws + (55u<<20));            // 8 MiB  (alias Pbuf+8M)

  fused_prep<<<2, 256, 0, stream>>>((const u32*)query, mask, flag, maskF);
  to_bf16_2<<<4096, 256, 0, stream>>>(query, key_value, flag, Qc, KVc);
  transpose_w2<<<dim3(48,16), 256, 0, stream>>>(Wq, Wkv, flag, WqT, WkvT);
  gemm_fused<<<dim3(24,32), 256, 0, stream>>>(Qc, WqT, bq, KVc, WkvT, bkv, flag, Qb, KVb);
  build_vt<<<dim3(16,16,4), 256, 0, stream>>>(KVb, Vt);
  attn_kern<<<dim3(16,16,4), 256, 0, stream>>>(Qb, KVb, Vt, maskF, Pbuf, Obuf, Sc, Fin);
  transpose_p<<<dim3(1024,4), 256, 0, stream>>>(Pbuf, Sc, Fin, attn_out);
  proj_out_k<<<dim3(1024), 256, 0, stream>>>(Obuf, Wp, bp, flag, out0);
}